// Round 1
// 197.945 us; speedup vs baseline: 1.1048x; 1.1048x over previous
//
#include <hip/hip_runtime.h>

typedef __attribute__((ext_vector_type(8))) short s8v;   // 8 bf16
typedef __attribute__((ext_vector_type(4))) short s4v;   // 4 bf16
typedef __attribute__((ext_vector_type(4))) float f4v;   // MFMA C/D

#define S_ 4096
#define E_ 1024
#define D_ 128

__device__ __forceinline__ unsigned short f2bf(float f) {
  unsigned int u = __float_as_uint(f);
  return (unsigned short)((u + 0x7FFFu + ((u >> 16) & 1u)) >> 16);
}

// ---- zero the accumulators -------------------------------------------------
__global__ __launch_bounds__(256) void zero_kernel(float* __restrict__ p) {
  const int i = blockIdx.x * 256 + threadIdx.x;
  float4 z = {0.f, 0.f, 0.f, 0.f};
  reinterpret_cast<float4*>(p)[i] = z;
}

// ---- W cvt+transpose: W[p][k][n] f32 -> Wt[p*128+n][k] bf16 ----------------
__global__ __launch_bounds__(256) void wcvt_kernel(
    const float* __restrict__ Wq, const float* __restrict__ Wk,
    const float* __restrict__ Wv, unsigned short* __restrict__ Wt) {
  __shared__ unsigned short T[64][72];
  const int p = blockIdx.y;
  const float* W = (p == 0) ? Wq : (p == 1) ? Wk : Wv;
  const int k0 = (blockIdx.x >> 1) * 64;
  const int n0 = (blockIdx.x & 1) * 64;
  const int t = threadIdx.x, rr = t >> 4, c4 = (t & 15) * 4;
#pragma unroll
  for (int i = 0; i < 4; ++i) {
    int kr = i * 16 + rr;
    float4 w = *reinterpret_cast<const float4*>(W + (size_t)(k0 + kr) * D_ + n0 + c4);
    T[c4 + 0][kr] = f2bf(w.x); T[c4 + 1][kr] = f2bf(w.y);
    T[c4 + 2][kr] = f2bf(w.z); T[c4 + 3][kr] = f2bf(w.w);
  }
  __syncthreads();
#pragma unroll
  for (int i = 0; i < 4; ++i) {
    int n = i * 16 + rr;
    s4v v;
    v[0] = (short)T[n][c4]; v[1] = (short)T[n][c4 + 1];
    v[2] = (short)T[n][c4 + 2]; v[3] = (short)T[n][c4 + 3];
    *reinterpret_cast<s4v*>(Wt + (size_t)(p * D_ + n0 + n) * E_ + k0 + c4) = v;
  }
}

// ---- fused QKV projection: 64x128xBK64 LDS GEMM, fixed pipeline ------------
// grid 768: cls = bid&7 (XCD class), mt = cls*32 + j/3, ng = j%3 — the 3
// n-groups of one M-tile share an XCD (x read once from HBM, L2-hit after).
// Pipeline: barrier / stage regs->LDS / barrier / ISSUE next loads / compute
// so global loads are in flight during compute (drained at next barrier).
__global__ __launch_bounds__(256) void proj_kernel(
    const float* __restrict__ x, const unsigned short* __restrict__ Wt,
    unsigned short* __restrict__ Qb, unsigned short* __restrict__ Kb,
    unsigned short* __restrict__ VT) {
  __shared__ __align__(16) unsigned short As[64 * 72];
  __shared__ __align__(16) unsigned short Bs[128 * 72];
  const int bid = blockIdx.x;
  const int cls = bid & 7, j = bid >> 3;
  const int m0 = (cls * 32 + j / 3) * 64, ng = j % 3;
  const int t = threadIdx.x;
  const int wv = t >> 6, lane = t & 63, quad = lane >> 4, l16 = lane & 15;
  const int wr = wv >> 1, wc = wv & 1;  // wave-tile 32x64

  f4v acc[2][4];
  const f4v fz = {0.f, 0.f, 0.f, 0.f};
#pragma unroll
  for (int i = 0; i < 2; ++i)
#pragma unroll
    for (int k = 0; k < 4; ++k) acc[i][k] = fz;

  const int arow = t >> 2, aq = t & 3;   // A: 64 rows x 4 k-quarters (16 f32)
  const int brow = t >> 1, bh = t & 1;   // B: 128 rows x 2 k-halves (32 bf16)
  const float* xg = x + (size_t)(m0 + arow) * E_ + aq * 16;
  const unsigned short* wg = Wt + (size_t)(ng * 128 + brow) * E_ + bh * 32;

  float4 xa[4];
  s8v wb[4];
#pragma unroll
  for (int i = 0; i < 4; ++i) xa[i] = *reinterpret_cast<const float4*>(xg + i * 4);
#pragma unroll
  for (int i = 0; i < 4; ++i) wb[i] = *reinterpret_cast<const s8v*>(wg + i * 8);

  for (int kk = 0; kk < E_; kk += 64) {
    __syncthreads();
#pragma unroll
    for (int i = 0; i < 2; ++i) {
      s8v av;
      av[0] = (short)f2bf(xa[2 * i].x);     av[1] = (short)f2bf(xa[2 * i].y);
      av[2] = (short)f2bf(xa[2 * i].z);     av[3] = (short)f2bf(xa[2 * i].w);
      av[4] = (short)f2bf(xa[2 * i + 1].x); av[5] = (short)f2bf(xa[2 * i + 1].y);
      av[6] = (short)f2bf(xa[2 * i + 1].z); av[7] = (short)f2bf(xa[2 * i + 1].w);
      *reinterpret_cast<s8v*>(As + arow * 72 + aq * 16 + i * 8) = av;
    }
#pragma unroll
    for (int i = 0; i < 4; ++i)
      *reinterpret_cast<s8v*>(Bs + brow * 72 + bh * 32 + i * 8) = wb[i];
    __syncthreads();
    if (kk + 64 < E_) {  // issue next-tile loads NOW; they fly during compute
#pragma unroll
      for (int i = 0; i < 4; ++i)
        xa[i] = *reinterpret_cast<const float4*>(xg + kk + 64 + i * 4);
#pragma unroll
      for (int i = 0; i < 4; ++i)
        wb[i] = *reinterpret_cast<const s8v*>(wg + kk + 64 + i * 8);
    }
#pragma unroll
    for (int ks = 0; ks < 2; ++ks) {
      s8v af[2], bf[4];
#pragma unroll
      for (int rt = 0; rt < 2; ++rt)
        af[rt] = *reinterpret_cast<const s8v*>(
            As + (wr * 32 + rt * 16 + l16) * 72 + ks * 32 + quad * 8);
#pragma unroll
      for (int ct = 0; ct < 4; ++ct)
        bf[ct] = *reinterpret_cast<const s8v*>(
            Bs + (wc * 64 + ct * 16 + l16) * 72 + ks * 32 + quad * 8);
#pragma unroll
      for (int rt = 0; rt < 2; ++rt)
#pragma unroll
        for (int ct = 0; ct < 4; ++ct)
          acc[rt][ct] = __builtin_amdgcn_mfma_f32_16x16x32_bf16(
              af[rt], bf[ct], acc[rt][ct], 0, 0, 0);
    }
  }

  if (ng < 2) {
    unsigned short* dst = ng ? Kb : Qb;
#pragma unroll
    for (int rt = 0; rt < 2; ++rt)
#pragma unroll
      for (int ct = 0; ct < 4; ++ct)
#pragma unroll
        for (int r = 0; r < 4; ++r)
          dst[(size_t)(m0 + wr * 32 + rt * 16 + quad * 4 + r) * D_ +
              wc * 64 + ct * 16 + l16] = f2bf(acc[rt][ct][r]);
  } else {
    const int b = m0 >> 12;
    const int s0 = (m0 & (S_ - 1)) + wr * 32;
#pragma unroll
    for (int rt = 0; rt < 2; ++rt)
#pragma unroll
      for (int ct = 0; ct < 4; ++ct) {
        s4v v;
        v[0] = (short)f2bf(acc[rt][ct][0]); v[1] = (short)f2bf(acc[rt][ct][1]);
        v[2] = (short)f2bf(acc[rt][ct][2]); v[3] = (short)f2bf(acc[rt][ct][3]);
        *reinterpret_cast<s4v*>(
            VT + ((size_t)b * D_ + wc * 64 + ct * 16 + l16) * S_ + s0 +
            rt * 16 + quad * 4) = v;
      }
  }
}

// ---- flash: 64-q blocks (16 q/wave), 512-key chunks, XOR-16 KS swizzle -----
// grid 1152: xcd = id&7 -> (batch, half-class); sub = heavy-first (qt, s)
// triangular decode over 64-row q-tiles. Tile group g (8 tiles) has g+1
// chunks/tile; cumulative before group g is 4g(g+1). Block = 64 q-rows x one
// 512-key chunk (<=8 64-key iters). Per-wave state halved vs previous
// version (16 q-rows/wave) so __launch_bounds__(256,4) holds VGPR<=128:
// 4 waves/SIMD x 4 blocks/CU (LDS 34KB) = 16 waves/CU resident.
__global__ __launch_bounds__(256, 4) void flash_kernel(
    const unsigned short* __restrict__ Qb, const unsigned short* __restrict__ Kb,
    const unsigned short* __restrict__ VT, float* __restrict__ Oacc,
    float* __restrict__ Lacc) {
  __shared__ __align__(16) unsigned short KS[64 * 128];
  __shared__ __align__(16) unsigned short VS[128 * 72];
  const int id = blockIdx.x;
  const int xcd = id & 7;
  const int b = xcd >> 1;
  const int sub = 287 - ((id >> 3) * 2 + (xcd & 1));  // heavy-first
  int g = 0;
#pragma unroll
  for (int gg = 0; gg < 7; ++gg)
    if (sub >= 4 * (gg + 1) * (gg + 2)) g = gg + 1;
  const int off = sub - 4 * g * (g + 1);
  const int qt = 8 * g + off / (g + 1);
  const int s = off % (g + 1);
  const int q0 = qt * 64;
  const int klo = s * 512;
  const int khi = min((s + 1) * 512, (qt + 1) * 64);

  const int t = threadIdx.x;
  const int wv = t >> 6, lane = t & 63, quad = lane >> 4, l16 = lane & 15;
  const int qrow0 = q0 + wv * 16;
  const float SCL2 = 0.03125f * 1.44269504088896340736f;  // (1/32)*log2(e)

  const unsigned short* Kbb = Kb + (size_t)b * S_ * D_;
  const unsigned short* Vbb = VT + (size_t)b * D_ * S_;

  s8v Qf[4];
#pragma unroll
  for (int ks = 0; ks < 4; ++ks)
    Qf[ks] = *reinterpret_cast<const s8v*>(
        Qb + ((size_t)b * S_ + qrow0 + l16) * D_ + ks * 32 + quad * 8);

  f4v O[8];
  const f4v fz = {0.f, 0.f, 0.f, 0.f};
#pragma unroll
  for (int nt = 0; nt < 8; ++nt) O[nt] = fz;
  float lt = 0.f;

  // staging: K rows krow+16i (granule kgb); V d-rows vrow (granules vgb+i)
  const int krow = t >> 4, kgb = t & 15;
  const int vrow = t >> 1, vgb = (t & 1) * 4;

  s8v kr[4], vr[4];
#pragma unroll
  for (int i = 0; i < 4; ++i) {
    kr[i] = *reinterpret_cast<const s8v*>(
        Kbb + (size_t)(klo + krow + 16 * i) * D_ + kgb * 8);
    vr[i] = *reinterpret_cast<const s8v*>(
        Vbb + (size_t)vrow * S_ + klo + (vgb + i) * 8);
  }

  for (int k0 = klo; k0 < khi; k0 += 64) {
    __syncthreads();
#pragma unroll
    for (int i = 0; i < 4; ++i) {
      const int r = krow + 16 * i;
      const int sig = (krow & 3) | ((((krow >> 3) + 2 * i) & 3) << 2);
      *reinterpret_cast<s8v*>(KS + r * 128 + ((kgb ^ sig) * 8)) = kr[i];
      *reinterpret_cast<s8v*>(VS + vrow * 72 + (vgb + i) * 8) = vr[i];
    }
    __syncthreads();
    if (k0 + 64 < khi) {  // issue next-tile loads; in flight during compute
#pragma unroll
      for (int i = 0; i < 4; ++i) {
        kr[i] = *reinterpret_cast<const s8v*>(
            Kbb + (size_t)(k0 + 64 + krow + 16 * i) * D_ + kgb * 8);
        vr[i] = *reinterpret_cast<const s8v*>(
            Vbb + (size_t)vrow * S_ + k0 + 64 + (vgb + i) * 8);
      }
    }

    if (k0 <= qrow0 + 15) {  // wave-uniform causal skip
      f4v St[2][2];  // [chunk c][s2]
#pragma unroll
      for (int c = 0; c < 2; ++c)
#pragma unroll
        for (int s2 = 0; s2 < 2; ++s2) St[c][s2] = fz;
#pragma unroll
      for (int ks = 0; ks < 4; ++ks)
#pragma unroll
        for (int c = 0; c < 2; ++c)
#pragma unroll
          for (int s2 = 0; s2 < 2; ++s2) {
            const int row = c * 32 + ((l16 >> 2) << 3) + s2 * 4 + (l16 & 3);
            s8v kf = *reinterpret_cast<const s8v*>(
                KS + row * 128 + (((ks * 4 + quad) ^ l16) * 8));
            St[c][s2] = __builtin_amdgcn_mfma_f32_16x16x32_bf16(
                kf, Qf[ks], St[c][s2], 0, 0, 0);
          }
      const bool full = (k0 + 63 <= qrow0);
      s8v pf[2];  // [c]
#pragma unroll
      for (int c = 0; c < 2; ++c) {
        float ladd = 0.f;
#pragma unroll
        for (int s2 = 0; s2 < 2; ++s2)
#pragma unroll
          for (int r = 0; r < 4; ++r) {
            float e = exp2f(St[c][s2][r] * SCL2);
            if (!full) {
              int key = k0 + c * 32 + quad * 8 + s2 * 4 + r;
              if (key > qrow0 + l16) e = 0.f;
            }
            ladd += e;
            pf[c][s2 * 4 + r] = (short)f2bf(e);
          }
        lt += ladd;
      }
#pragma unroll
      for (int c = 0; c < 2; ++c)
#pragma unroll
        for (int nt = 0; nt < 8; ++nt) {
          s8v vf = *reinterpret_cast<const s8v*>(
              VS + (nt * 16 + l16) * 72 + (c * 4 + quad) * 8);
          O[nt] = __builtin_amdgcn_mfma_f32_16x16x32_bf16(
              pf[c], vf, O[nt], 0, 0, 0);
        }
    }
  }

  // epilogue: atomically accumulate partial (O, l)
  lt += __shfl_xor(lt, 16);
  lt += __shfl_xor(lt, 32);
  float* Ob = Oacc + (size_t)b * S_ * D_;
#pragma unroll
  for (int nt = 0; nt < 8; ++nt)
#pragma unroll
    for (int r = 0; r < 4; ++r)
      atomicAdd(&Ob[(size_t)(qrow0 + quad * 4 + r) * D_ + nt * 16 + l16],
                O[nt][r]);
  if (lane < 16) atomicAdd(&Lacc[(size_t)b * S_ + qrow0 + l16], lt);
}

// ---- normalize: out = Oacc / Lacc ------------------------------------------
__global__ __launch_bounds__(256) void norm_kernel(
    const float* __restrict__ Oacc, const float* __restrict__ Lacc,
    float* __restrict__ out) {
  const int idx = blockIdx.x * 256 + threadIdx.x;
  const int base = idx * 4;
  const int row = base >> 7;
  float4 o = reinterpret_cast<const float4*>(Oacc)[idx];
  float L = Lacc[row];
  float4 r;
  r.x = o.x / L; r.y = o.y / L; r.z = o.z / L; r.w = o.w / L;
  reinterpret_cast<float4*>(out)[idx] = r;
}

extern "C" void kernel_launch(void* const* d_in, const int* in_sizes, int n_in,
                              void* d_out, int out_size, void* d_ws, size_t ws_size,
                              hipStream_t stream) {
  const float* x = (const float*)d_in[0];
  const float* Wq = (const float*)d_in[1];
  const float* Wk = (const float*)d_in[2];
  const float* Wv = (const float*)d_in[3];
  float* out = (float*)d_out;

  char* ws = (char*)d_ws;
  unsigned short* Qb = (unsigned short*)ws;                           // 4 MB
  unsigned short* Kb = (unsigned short*)(ws + (((size_t)4) << 20));   // 4 MB
  unsigned short* VT = (unsigned short*)(ws + (((size_t)8) << 20));   // 4 MB
  unsigned short* Wt = (unsigned short*)(ws + (((size_t)12) << 20));  // 0.75 MB
  float* Oacc = (float*)(ws + (((size_t)13) << 20));                  // 8 MB
  float* Lacc = (float*)(ws + (((size_t)21) << 20));                  // 64 KB

  zero_kernel<<<2064, 256, 0, stream>>>(Oacc);  // covers Oacc+Lacc contiguous
  wcvt_kernel<<<dim3(32, 3), 256, 0, stream>>>(Wq, Wk, Wv, Wt);
  proj_kernel<<<768, 256, 0, stream>>>(x, Wt, Qb, Kb, VT);
  flash_kernel<<<1152, 256, 0, stream>>>(Qb, Kb, VT, Oacc, Lacc);
  norm_kernel<<<2048, 256, 0, stream>>>(Oacc, Lacc, out);
}